// Round 7
// baseline (192.236 us; speedup 1.0000x reference)
//
#include <hip/hip_runtime.h>

// BilinearGridSample: img (N=8, C=64, H=256, W=256) f32, points (N,384,384,2) f32
// out (N, C, 384*384) f32.  mmcv bilinear_grid_sample, align_corners=False.
//
// Phase-split channels-last design (phases q = (n, cg), cg = 32-channel group):
//  (1) repack: img -> ws[q][hw][32ch] bf16. Phase-major grid, XCD-pinned
//      (bid%8): each XCD produces exactly the ws slices its sample phases
//      read. thread=(pixel,quarter) -> wave stores are 1KB contiguous.
//  (2) sample: XCD-pinned phases (4.2MB slice == one XCD L2). 4 lanes per
//      point gather the 4x16B quarters of each 64B corner run (16 unique
//      lines/inst). Output through an LDS transpose so NT stores are
//      8x256B contiguous row segments per wave-inst (full HBM lines) instead
//      of 32 scattered 64B segments.

#define NN 8
#define CC 64
#define HH 256
#define WW 256
#define HWSZ (HH * WW)
#define PP (384 * 384)      // 147456
#define CHUNKS (PP / 64)    // 2304 point-chunks (64 points/block) per phase
#define NQ (NN * 2)         // 16 phases
#define PCHUNKS (HWSZ / 64) // 1024 pixel-chunks per phase (repack)
#define LDSW 66             // padded row stride (floats); 2-way banks only

typedef float f32x4 __attribute__((ext_vector_type(4)));

__device__ __forceinline__ unsigned int bf16rne(float f) {
    unsigned int u = __float_as_uint(f);
    return (u + 0x7FFFu + ((u >> 16) & 1u)) >> 16;
}

// ---- phase 1: img (N,C,H,W) f32 -> ws[q][hw][32ch] bf16, XCD-pinned ----
__global__ __launch_bounds__(256) void repack_kernel(
    const float* __restrict__ img, unsigned int* __restrict__ ws)
{
    const int bid = blockIdx.x;              // 0 .. NQ*PCHUNKS-1
    const int xcd = bid & 7;
    const int seq = bid >> 3;                // 0 .. 2*PCHUNKS-1
    const int q   = xcd + 8 * (seq / PCHUNKS);
    const int hw0 = (seq % PCHUNKS) * 64;
    const int n   = q >> 1;
    const int cg  = q & 1;
    const int qt  = threadIdx.x & 3;         // channel quarter (8 ch)
    const int hw  = hw0 + (threadIdx.x >> 2);

    const float* src = img + ((size_t)(n * CC + cg * 32 + qt * 8)) * HWSZ + hw;
    unsigned int buf[4];
    #pragma unroll
    for (int k = 0; k < 4; ++k) {
        float f0 = src[(size_t)(2 * k) * HWSZ];
        float f1 = src[(size_t)(2 * k + 1) * HWSZ];
        buf[k] = bf16rne(f0) | (bf16rne(f1) << 16);
    }
    uint4* dst = (uint4*)ws + ((size_t)q * HWSZ + hw) * 4 + qt;
    *dst = make_uint4(buf[0], buf[1], buf[2], buf[3]);
}

// ---- phase 2: XCD-pinned gather; 4 lanes/point; LDS-transposed stores ----
__global__ __launch_bounds__(256) void sample_cl_kernel(
    const unsigned int* __restrict__ ws,   // (NQ, HW, 16 uints)
    const float* __restrict__ points,      // (N, P, 2)
    float* __restrict__ out)               // (N, C, P)
{
    __shared__ float lds[32 * LDSW];

    const int bid  = blockIdx.x;           // 0 .. NQ*CHUNKS-1
    const int xcd  = bid & 7;
    const int seq  = bid >> 3;             // 0 .. 2*CHUNKS-1
    const int q    = xcd + 8 * (seq / CHUNKS);   // phase 0..15
    const int chunk = seq % CHUNKS;
    const int n  = q >> 1;
    const int cg = q & 1;
    const int qt = threadIdx.x & 3;              // channel quarter (8 ch)
    const int pl = threadIdx.x >> 2;             // point within chunk (0..63)
    const int p  = chunk * 64 + pl;

    float2 pt = ((const float2*)points)[(size_t)n * PP + p];
    float x = ((pt.x + 1.0f) * (float)WW - 1.0f) * 0.5f;
    float y = ((pt.y + 1.0f) * (float)HH - 1.0f) * 0.5f;

    float x0f = floorf(x);
    float y0f = floorf(y);
    float fx = x - x0f;
    float fy = y - y0f;
    int x0 = (int)x0f;
    int y0 = (int)y0f;
    int x1 = x0 + 1;
    int y1 = y0 + 1;

    bool vx0 = (x0 >= 0) && (x0 < WW);
    bool vx1 = (x1 >= 0) && (x1 < WW);
    bool vy0 = (y0 >= 0) && (y0 < HH);
    bool vy1 = (y1 >= 0) && (y1 < HH);

    float wa = (1.0f - fx) * (1.0f - fy);  // (y0, x0)
    float wb = (1.0f - fx) * fy;           // (y1, x0)
    float wc = fx * (1.0f - fy);           // (y0, x1)
    float wd = fx * fy;                    // (y1, x1)

    wa = (vx0 && vy0) ? wa : 0.0f;
    wb = (vx0 && vy1) ? wb : 0.0f;
    wc = (vx1 && vy0) ? wc : 0.0f;
    wd = (vx1 && vy1) ? wd : 0.0f;

    int cx0 = min(max(x0, 0), WW - 1);
    int cx1 = min(max(x1, 0), WW - 1);
    int cy0 = min(max(y0, 0), HH - 1);
    int cy1 = min(max(y1, 0), HH - 1);

    const uint4* base = (const uint4*)ws + (size_t)q * (HWSZ * 4) + qt;
    uint4 A = base[(size_t)(cy0 * WW + cx0) * 4];
    uint4 B = base[(size_t)(cy1 * WW + cx0) * 4];
    uint4 C = base[(size_t)(cy0 * WW + cx1) * 4];
    uint4 D = base[(size_t)(cy1 * WW + cx1) * 4];

    const unsigned int aw[4] = {A.x, A.y, A.z, A.w};
    const unsigned int bw[4] = {B.x, B.y, B.z, B.w};
    const unsigned int cw[4] = {C.x, C.y, C.z, C.w};
    const unsigned int dw[4] = {D.x, D.y, D.z, D.w};
    #pragma unroll
    for (int j = 0; j < 4; ++j) {    // each uint = 2 channels
        float a0 = __uint_as_float(aw[j] << 16);
        float a1 = __uint_as_float(aw[j] & 0xFFFF0000u);
        float b0 = __uint_as_float(bw[j] << 16);
        float b1 = __uint_as_float(bw[j] & 0xFFFF0000u);
        float c0 = __uint_as_float(cw[j] << 16);
        float c1 = __uint_as_float(cw[j] & 0xFFFF0000u);
        float d0 = __uint_as_float(dw[j] << 16);
        float d1 = __uint_as_float(dw[j] & 0xFFFF0000u);
        float v0 = a0 * wa + b0 * wb + c0 * wc + d0 * wd;
        float v1 = a1 * wa + b1 * wb + c1 * wc + d1 * wd;
        lds[(qt * 8 + 2 * j)     * LDSW + pl] = v0;
        lds[(qt * 8 + 2 * j + 1) * LDSW + pl] = v1;
    }

    __syncthreads();

    // transposed write-out: thread t handles row r = t>>3, cols c8 = (t&7)*8
    const int r  = threadIdx.x >> 3;        // 0..31 (channel within cg)
    const int c8 = (threadIdx.x & 7) * 8;   // 0..56 (point within chunk)
    const float* srcl = &lds[r * LDSW + c8];
    f32x4 f0 = {srcl[0], srcl[1], srcl[2], srcl[3]};
    f32x4 f1 = {srcl[4], srcl[5], srcl[6], srcl[7]};
    float* op = out + ((size_t)(n * CC) + cg * 32 + r) * PP + chunk * 64 + c8;
    __builtin_nontemporal_store(f0, (f32x4*)op);
    __builtin_nontemporal_store(f1, (f32x4*)(op + 4));
}

// ---- fallback (round-2 kernel) if ws is too small ----
__global__ __launch_bounds__(256) void grid_sample_fallback(
    const float* __restrict__ img,
    const float* __restrict__ points,
    float* __restrict__ out)
{
    const int p  = blockIdx.x * 256 + threadIdx.x;
    const int c0 = blockIdx.y * 2;
    const int n  = blockIdx.z;

    float2 pt = ((const float2*)points)[(size_t)n * PP + p];
    float x = ((pt.x + 1.0f) * (float)WW - 1.0f) * 0.5f;
    float y = ((pt.y + 1.0f) * (float)HH - 1.0f) * 0.5f;
    float x0f = floorf(x), y0f = floorf(y);
    float fx = x - x0f, fy = y - y0f;
    int x0 = (int)x0f, y0 = (int)y0f, x1 = x0 + 1, y1 = y0 + 1;
    bool vx0 = (x0 >= 0) && (x0 < WW), vx1 = (x1 >= 0) && (x1 < WW);
    bool vy0 = (y0 >= 0) && (y0 < HH), vy1 = (y1 >= 0) && (y1 < HH);
    float wa = (1.0f - fx) * (1.0f - fy), wb = (1.0f - fx) * fy;
    float wc = fx * (1.0f - fy), wd = fx * fy;
    wa = (vx0 && vy0) ? wa : 0.0f;
    wb = (vx0 && vy1) ? wb : 0.0f;
    wc = (vx1 && vy0) ? wc : 0.0f;
    wd = (vx1 && vy1) ? wd : 0.0f;
    int cx0 = min(max(x0, 0), WW - 1), cx1 = min(max(x1, 0), WW - 1);
    int cy0 = min(max(y0, 0), HH - 1), cy1 = min(max(y1, 0), HH - 1);
    int ia = cy0 * WW + cx0, ib = cy1 * WW + cx0;
    int ic = cy0 * WW + cx1, id = cy1 * WW + cx1;
    const float* plane = img + ((size_t)(n * CC + c0)) * HWSZ;
    float* outp = out + ((size_t)(n * CC + c0)) * PP + p;
    #pragma unroll
    for (int k = 0; k < 2; ++k) {
        float v = plane[ia] * wa + plane[ib] * wb + plane[ic] * wc + plane[id] * wd;
        __builtin_nontemporal_store(v, outp);
        plane += HWSZ;
        outp  += PP;
    }
}

extern "C" void kernel_launch(void* const* d_in, const int* in_sizes, int n_in,
                              void* d_out, int out_size, void* d_ws, size_t ws_size,
                              hipStream_t stream) {
    const float* img = (const float*)d_in[0];
    const float* points = (const float*)d_in[1];
    float* out = (float*)d_out;

    const size_t ws_needed = (size_t)NN * HWSZ * CC * 2;  // 67,108,864 B bf16
    if (ws_size >= ws_needed) {
        unsigned int* ws = (unsigned int*)d_ws;
        repack_kernel<<<NQ * PCHUNKS, 256, 0, stream>>>(img, ws);      // 16384 blocks
        sample_cl_kernel<<<NQ * CHUNKS, 256, 0, stream>>>(ws, points, out); // 36864 blocks
    } else {
        dim3 g(PP / 256, CC / 2, NN);
        grid_sample_fallback<<<g, 256, 0, stream>>>(img, points, out);
    }
}

// Round 8
// 130.830 us; speedup vs baseline: 1.4694x; 1.4694x over previous
//
#include <hip/hip_runtime.h>

// BilinearGridSample: img (N=8, C=64, H=256, W=256) f32, points (N,384,384,2) f32
// out (N, C, 384*384) f32.  mmcv bilinear_grid_sample, align_corners=False.
//
// Phase-split channels-last design (ROUND-5 KNOWN-GOOD, 130.7us):
//  (1) repack img -> ws[n][cg][hw][32ch] bf16 (cg = channel group of 32).
//      One corner gather = 64 B line, fully consumed. Reads 256B-contiguous
//      per wave-inst; store segmentation costs only ~5us (measured r7: "fixing"
//      it with phase-major repack + LDS-transpose sample REGRESSED to 192us).
//  (2) sample: 16 phases q=(n,cg) pinned to XCD q%8 (bid%8 round-robin);
//      per-phase footprint 4.2MB == one XCD L2 -> gather re-reads are L2 hits.
//      4 lanes cooperate per point: each gather inst covers 16 unique 64B
//      lines (4x16B quarters per corner run).
// Structural floor ~125us: 95us two-phase HBM traffic + ~30us TA segment
// serialization (4 corner-lines/point irreducible for random points).

#define NN 8
#define CC 64
#define HH 256
#define WW 256
#define HWSZ (HH * WW)
#define PP (384 * 384)      // 147456
#define CHUNKS (PP / 64)    // 2304 point-chunks (64 points/block) per phase
#define NQ (NN * 2)         // 16 phases

__device__ __forceinline__ unsigned int bf16rne(float f) {
    unsigned int u = __float_as_uint(f);
    return (u + 0x7FFFu + ((u >> 16) & 1u)) >> 16;
}

// ---- phase 1: (N,C,H,W) f32 -> ws[(n*2+cg)][hw][32ch] bf16 ----
__global__ __launch_bounds__(256) void repack_kernel(
    const float* __restrict__ img, unsigned int* __restrict__ ws)
{
    const int hw = blockIdx.x * 256 + threadIdx.x;
    const int n  = blockIdx.y;
    const float* src = img + (size_t)n * CC * HWSZ + hw;

    unsigned int buf[CC / 2];
    #pragma unroll
    for (int c2 = 0; c2 < CC / 2; ++c2) {
        float f0 = src[(size_t)(2 * c2) * HWSZ];
        float f1 = src[(size_t)(2 * c2 + 1) * HWSZ];
        buf[c2] = bf16rne(f0) | (bf16rne(f1) << 16);
    }
    #pragma unroll
    for (int cg = 0; cg < 2; ++cg) {
        uint4* dst = (uint4*)(ws + ((size_t)(n * 2 + cg) * HWSZ + hw) * 16);
        #pragma unroll
        for (int k = 0; k < 4; ++k)
            dst[k] = make_uint4(buf[cg * 16 + 4 * k],     buf[cg * 16 + 4 * k + 1],
                                buf[cg * 16 + 4 * k + 2], buf[cg * 16 + 4 * k + 3]);
    }
}

// ---- phase 2: XCD-pinned gather; 4 lanes per point (one 16B quarter each) ----
__global__ __launch_bounds__(256) void sample_cl_kernel(
    const unsigned int* __restrict__ ws,   // (NQ, HW, 16 uints)
    const float* __restrict__ points,      // (N, P, 2)
    float* __restrict__ out)               // (N, C, P)
{
    const int bid  = blockIdx.x;           // 0 .. NQ*CHUNKS-1
    const int xcd  = bid & 7;
    const int seq  = bid >> 3;             // 0 .. 2*CHUNKS-1
    const int q    = xcd + 8 * (seq / CHUNKS);   // phase 0..15
    const int chunk = seq % CHUNKS;
    const int n  = q >> 1;
    const int cg = q & 1;
    const int qt = threadIdx.x & 3;              // channel quarter (8 ch)
    const int p  = chunk * 64 + (threadIdx.x >> 2);

    float2 pt = ((const float2*)points)[(size_t)n * PP + p];
    float x = ((pt.x + 1.0f) * (float)WW - 1.0f) * 0.5f;
    float y = ((pt.y + 1.0f) * (float)HH - 1.0f) * 0.5f;

    float x0f = floorf(x);
    float y0f = floorf(y);
    float fx = x - x0f;
    float fy = y - y0f;
    int x0 = (int)x0f;
    int y0 = (int)y0f;
    int x1 = x0 + 1;
    int y1 = y0 + 1;

    bool vx0 = (x0 >= 0) && (x0 < WW);
    bool vx1 = (x1 >= 0) && (x1 < WW);
    bool vy0 = (y0 >= 0) && (y0 < HH);
    bool vy1 = (y1 >= 0) && (y1 < HH);

    float wa = (1.0f - fx) * (1.0f - fy);  // (y0, x0)
    float wb = (1.0f - fx) * fy;           // (y1, x0)
    float wc = fx * (1.0f - fy);           // (y0, x1)
    float wd = fx * fy;                    // (y1, x1)

    wa = (vx0 && vy0) ? wa : 0.0f;
    wb = (vx0 && vy1) ? wb : 0.0f;
    wc = (vx1 && vy0) ? wc : 0.0f;
    wd = (vx1 && vy1) ? wd : 0.0f;

    int cx0 = min(max(x0, 0), WW - 1);
    int cx1 = min(max(x1, 0), WW - 1);
    int cy0 = min(max(y0, 0), HH - 1);
    int cy1 = min(max(y1, 0), HH - 1);

    const uint4* base = (const uint4*)ws + (size_t)q * (HWSZ * 4) + qt;
    const uint4* pa = base + (size_t)(cy0 * WW + cx0) * 4;
    const uint4* pb = base + (size_t)(cy1 * WW + cx0) * 4;
    const uint4* pc = base + (size_t)(cy0 * WW + cx1) * 4;
    const uint4* pd = base + (size_t)(cy1 * WW + cx1) * 4;

    uint4 A = *pa;
    uint4 B = *pb;
    uint4 C = *pc;
    uint4 D = *pd;

    // this thread owns channels cg*32 + qt*8 + [0,8)
    float* outp = out + ((size_t)(n * CC) + cg * 32 + qt * 8) * PP + p;

    const unsigned int aw[4] = {A.x, A.y, A.z, A.w};
    const unsigned int bw[4] = {B.x, B.y, B.z, B.w};
    const unsigned int cw[4] = {C.x, C.y, C.z, C.w};
    const unsigned int dw[4] = {D.x, D.y, D.z, D.w};
    #pragma unroll
    for (int j = 0; j < 4; ++j) {    // each uint = 2 channels
        float a0 = __uint_as_float(aw[j] << 16);
        float a1 = __uint_as_float(aw[j] & 0xFFFF0000u);
        float b0 = __uint_as_float(bw[j] << 16);
        float b1 = __uint_as_float(bw[j] & 0xFFFF0000u);
        float c0 = __uint_as_float(cw[j] << 16);
        float c1 = __uint_as_float(cw[j] & 0xFFFF0000u);
        float d0 = __uint_as_float(dw[j] << 16);
        float d1 = __uint_as_float(dw[j] & 0xFFFF0000u);
        float v0 = a0 * wa + b0 * wb + c0 * wc + d0 * wd;
        float v1 = a1 * wa + b1 * wb + c1 * wc + d1 * wd;
        __builtin_nontemporal_store(v0, outp + (size_t)(2 * j) * PP);
        __builtin_nontemporal_store(v1, outp + (size_t)(2 * j + 1) * PP);
    }
}

// ---- fallback (round-2 kernel) if ws is too small ----
__global__ __launch_bounds__(256) void grid_sample_fallback(
    const float* __restrict__ img,
    const float* __restrict__ points,
    float* __restrict__ out)
{
    const int p  = blockIdx.x * 256 + threadIdx.x;
    const int c0 = blockIdx.y * 2;
    const int n  = blockIdx.z;

    float2 pt = ((const float2*)points)[(size_t)n * PP + p];
    float x = ((pt.x + 1.0f) * (float)WW - 1.0f) * 0.5f;
    float y = ((pt.y + 1.0f) * (float)HH - 1.0f) * 0.5f;
    float x0f = floorf(x), y0f = floorf(y);
    float fx = x - x0f, fy = y - y0f;
    int x0 = (int)x0f, y0 = (int)y0f, x1 = x0 + 1, y1 = y0 + 1;
    bool vx0 = (x0 >= 0) && (x0 < WW), vx1 = (x1 >= 0) && (x1 < WW);
    bool vy0 = (y0 >= 0) && (y0 < HH), vy1 = (y1 >= 0) && (y1 < HH);
    float wa = (1.0f - fx) * (1.0f - fy), wb = (1.0f - fx) * fy;
    float wc = fx * (1.0f - fy), wd = fx * fy;
    wa = (vx0 && vy0) ? wa : 0.0f;
    wb = (vx0 && vy1) ? wb : 0.0f;
    wc = (vx1 && vy0) ? wc : 0.0f;
    wd = (vx1 && vy1) ? wd : 0.0f;
    int cx0 = min(max(x0, 0), WW - 1), cx1 = min(max(x1, 0), WW - 1);
    int cy0 = min(max(y0, 0), HH - 1), cy1 = min(max(y1, 0), HH - 1);
    int ia = cy0 * WW + cx0, ib = cy1 * WW + cx0;
    int ic = cy0 * WW + cx1, id = cy1 * WW + cx1;
    const float* plane = img + ((size_t)(n * CC + c0)) * HWSZ;
    float* outp = out + ((size_t)(n * CC + c0)) * PP + p;
    #pragma unroll
    for (int k = 0; k < 2; ++k) {
        float v = plane[ia] * wa + plane[ib] * wb + plane[ic] * wc + plane[id] * wd;
        __builtin_nontemporal_store(v, outp);
        plane += HWSZ;
        outp  += PP;
    }
}

extern "C" void kernel_launch(void* const* d_in, const int* in_sizes, int n_in,
                              void* d_out, int out_size, void* d_ws, size_t ws_size,
                              hipStream_t stream) {
    const float* img = (const float*)d_in[0];
    const float* points = (const float*)d_in[1];
    float* out = (float*)d_out;

    const size_t ws_needed = (size_t)NN * HWSZ * CC * 2;  // 67,108,864 B bf16
    if (ws_size >= ws_needed) {
        unsigned int* ws = (unsigned int*)d_ws;
        dim3 g1(HWSZ / 256, NN);
        repack_kernel<<<g1, 256, 0, stream>>>(img, ws);
        dim3 g2(NQ * CHUNKS);  // 36,864 blocks, 1D for XCD pinning
        sample_cl_kernel<<<g2, 256, 0, stream>>>(ws, points, out);
    } else {
        dim3 g(PP / 256, CC / 2, NN);
        grid_sample_fallback<<<g, 256, 0, stream>>>(img, points, out);
    }
}